// Round 5
// baseline (385.870 us; speedup 1.0000x reference)
//
#include <hip/hip_runtime.h>

// Problem constants (B=2, S=8192, IN=2048, OUT=2048, L=4, R=32)
#define M_DIM 16384
#define N_DIM 2048
#define K_DIM 2048
#define L_AD 4
#define R_AD 32

typedef __bf16 bf16_t;
typedef bf16_t bf16x8 __attribute__((ext_vector_type(8)));
typedef bf16_t bf16x4 __attribute__((ext_vector_type(4)));
typedef float f32x4 __attribute__((ext_vector_type(4)));
typedef float f32x16 __attribute__((ext_vector_type(16)));

#define BM 128
#define BN 128
#define BK 64

__device__ __forceinline__ void async_load16(const void* g, void* l) {
  __builtin_amdgcn_global_load_lds(
      (const __attribute__((address_space(1))) unsigned int*)g,
      (__attribute__((address_space(3))) unsigned int*)l, 16, 0, 0);
}

// ---------------------------------------------------------------------------
// Kernel 0: x fp32 -> bf16 (33.5M elems). Pure bandwidth pass.
// ---------------------------------------------------------------------------
__global__ __launch_bounds__(256) void convert_x_kernel(
    const float* __restrict__ X, bf16_t* __restrict__ Xb) {
  const size_t base = ((size_t)blockIdx.x * 256 + threadIdx.x) * 8;
  f32x4 lo = *(const f32x4*)(X + base);
  f32x4 hi = *(const f32x4*)(X + base + 4);
  bf16x8 v;
  v[0] = (bf16_t)lo[0]; v[1] = (bf16_t)lo[1];
  v[2] = (bf16_t)lo[2]; v[3] = (bf16_t)lo[3];
  v[4] = (bf16_t)hi[0]; v[5] = (bf16_t)hi[1];
  v[6] = (bf16_t)hi[2]; v[7] = (bf16_t)hi[3];
  *(bf16x8*)(Xb + base) = v;
}

// ---------------------------------------------------------------------------
// Kernel 1: Weff[n,k] = bf16( W[n,k] + sum_l scale_l * sum_r ups[l,n,r]*downs[l,r,k] )
// ---------------------------------------------------------------------------
__global__ __launch_bounds__(256) void build_weff_kernel(
    const float* __restrict__ W, const float* __restrict__ downs,
    const float* __restrict__ ups, const float* __restrict__ scales,
    bf16_t* __restrict__ weff) {
  __shared__ float up_s[64 * 129];
  __shared__ float down_s[128 * 64];
  const int t = threadIdx.x;
  const int n0 = blockIdx.y * 64;
  const int k0 = blockIdx.x * 64;

  for (int l = 0; l < L_AD; ++l) {
    const float sc = scales[l];
    const float* up_l = ups + (size_t)l * N_DIM * R_AD;
    #pragma unroll
    for (int j = 0; j < 8; ++j) {
      int flat = j * 256 + t;
      int nl = flat >> 5, r = flat & 31;
      up_s[nl * 129 + l * 32 + r] = sc * up_l[(size_t)(n0 + nl) * R_AD + r];
    }
  }
  #pragma unroll
  for (int j = 0; j < 32; ++j) {
    int flat = j * 256 + t;
    int lr = flat >> 6, kk = flat & 63;
    down_s[lr * 64 + kk] = downs[(size_t)lr * K_DIM + k0 + kk];
  }
  __syncthreads();

  const int tn = t >> 4, tk = t & 15;
  float acc[4][4] = {};
  for (int lr = 0; lr < L_AD * R_AD; ++lr) {
    f32x4 b = *(const f32x4*)&down_s[lr * 64 + tk * 4];
    #pragma unroll
    for (int u = 0; u < 4; ++u) {
      float a = up_s[(tn * 4 + u) * 129 + lr];
      #pragma unroll
      for (int v = 0; v < 4; ++v) acc[u][v] += a * b[v];
    }
  }
  #pragma unroll
  for (int u = 0; u < 4; ++u) {
    int n = n0 + tn * 4 + u;
    f32x4 wv = *(const f32x4*)&W[(size_t)n * K_DIM + k0 + tk * 4];
    bf16x4 o;
    #pragma unroll
    for (int v = 0; v < 4; ++v) o[v] = (bf16_t)(acc[u][v] + wv[v]);
    *(bf16x4*)&weff[(size_t)n * K_DIM + k0 + tk * 4] = o;
  }
}

// ---------------------------------------------------------------------------
// Kernel 2 (fast path): 256x256 tile, BK=64, 8 waves (2Mx4N), 8-phase
// schedule with INTRA-PHASE read/MFMA overlap. R5 changes vs R4 (45% util):
//  - Cycle model: phase = 1214 cyc, MFMA = 621 -> read-drain serialized
//    with MFMA inside the lockstep phase. Fix: reads ordered by k-step,
//    interleaved lgkmcnt(9/6/3/0) + MFMA groups so ksN's MFMA runs while
//    ks>N reads are in flight (DS lgkm returns are in-order; the
//    global_load_lds stages count vmcnt, not lgkm).
//  - MFMA shape 32x32x16 (2495 vs 2075 TF ceiling; frag math and C/D
//    layout proven in this problem's R0 kernel). 8 MFMA/phase in 4
//    ks-groups of 2.
// Stage plan and vmcnt(4) points identical to R4 (audited):
//   ph1: buf1.A0<-2j+1  ph2: buf1.A1<-2j+1  ph3: buf0.B0<-2j+2
//   ph4: buf0.B1<-2j+2  ph5: buf0.A0<-2j+2  ph6: buf0.A1<-2j+2
//   ph7: buf1.B0<-2j+3  ph8: buf1.B1<-2j+3
//   vmcnt(4) at ph4/ph8 completes exactly the 4 half-regions of the buffer
//   consumed next. All reads drain (last group lgkm(0)) before barrier2;
//   overwritten regions last read >=1 barrier+lgkm before their STG.
//
// LDS: sm[buf(2)][op A/B(2)][16384 bf16] = 128 KiB.
//   Half h of a (256x64) tile = rows h*128..+127, stored as 1024 16B-chunks:
//   chunk d: row = d>>3, slot = d&7 holds global k-octet  c = slot ^ (row&7).
// Frags (32x32x16): A/B row = lane&31, k-octet = (ks*2 + lane>>5)^(row&7).
//   C/D: col=lane&31, row=(reg&3)+8*(reg>>2)+4*(lane>>5).
// ---------------------------------------------------------------------------
#define BARRIER() __builtin_amdgcn_s_barrier()
#define SCHEDB() __builtin_amdgcn_sched_barrier(0)
#define LGKM(N) asm volatile("s_waitcnt lgkmcnt(" #N ")" ::: "memory")
#define VMCNT4() asm volatile("s_waitcnt vmcnt(4)" ::: "memory")
#define VMCNT0() asm volatile("s_waitcnt vmcnt(0)" ::: "memory")

__global__ __launch_bounds__(512, 2) void gemm_bf16_256(
    const bf16_t* __restrict__ Xb, const bf16_t* __restrict__ Wb,
    const float* __restrict__ bias, float* __restrict__ out) {
  __shared__ __align__(16) bf16_t sm[2][2][16384];

  // bijective XCD swizzle: nwg=512 (%8==0); each XCD gets an 8x8 tile patch.
  const int orig = blockIdx.x;
  const int swz = (orig & 7) * 64 + (orig >> 3);
  const int m0 = (swz >> 3) * 256;
  const int n0 = (swz & 7) * 256;

  const int t = threadIdx.x;
  const int l = t & 63;
  const int w = t >> 6;
  const int wm = w >> 2, wn = w & 3;
  const int l5 = l & 31;      // row within 32x32 frag
  const int half = l >> 5;    // k-octet half selector

  // staging geometry: thread stages chunks d0 and d0+512 of each half-tile
  const int d0 = w * 64 + l;
  const int row0 = d0 >> 3;
  const int c0 = (d0 & 7) ^ (row0 & 7);
  const bf16_t* Ab = Xb + (size_t)(m0 + row0) * K_DIM + c0 * 8;
  const bf16_t* Bb = Wb + (size_t)(n0 + row0) * K_DIM + c0 * 8;

  float bn[2];
  #pragma unroll
  for (int g = 0; g < 2; ++g) bn[g] = bias[n0 + wn * 64 + g * 32 + l5];

  f32x16 acc[4][2] = {};           // [f 0..3][g 0..1], AGPRs
  bf16x8 aLo[2][4], aHi[2][4], bB[2][4];  // [frag][ks]

#define STG(Gb, B_, OP, H, KT)                                                 \
  do {                                                                         \
    async_load16((Gb) + ((size_t)(H)*128) * K_DIM + (size_t)(KT)*64,           \
                 &sm[B_][OP][(H)*8192 + d0 * 8]);                              \
    async_load16((Gb) + ((size_t)(H)*128 + 64) * K_DIM + (size_t)(KT)*64,      \
                 &sm[B_][OP][(H)*8192 + (d0 + 512) * 8]);                      \
  } while (0)

// A frag f (0..3 => rows wm*128 + f*32 + l5), k-step ks. h = wm.
#define RA(dst, fi, F, ks, B_)                                                 \
  do {                                                                         \
    const int rl_ = (F)*32 + l5;                                               \
    const int sl_ = ((ks)*2 + half) ^ (rl_ & 7);                               \
    dst[fi][ks] = *(const bf16x8*)&sm[B_][0][wm * 8192 + (rl_ * 8 + sl_) * 8]; \
  } while (0)

// B frag g (rows wn*64 + g*32 + l5), k-step ks.
#define RB(gi, ks, B_)                                                         \
  do {                                                                         \
    const int R_ = wn * 64 + (gi)*32 + l5;                                     \
    const int rl_ = R_ & 127, h_ = R_ >> 7;                                    \
    const int sl_ = ((ks)*2 + half) ^ (rl_ & 7);                               \
    bB[gi][ks] = *(const bf16x8*)&sm[B_][1][h_ * 8192 + (rl_ * 8 + sl_) * 8];  \
  } while (0)

// one ks-group: 2 MFMA (f-pair FA,FA+1 vs col G) at k-step ks
#define MF2(AARR, FA, G, ks)                                                   \
  do {                                                                         \
    acc[(FA) + 0][G] = __builtin_amdgcn_mfma_f32_32x32x16_bf16(                \
        AARR[0][ks], bB[G][ks], acc[(FA) + 0][G], 0, 0, 0);                    \
    acc[(FA) + 1][G] = __builtin_amdgcn_mfma_f32_32x32x16_bf16(                \
        AARR[1][ks], bB[G][ks], acc[(FA) + 1][G], 0, 0, 0);                    \
  } while (0)

  // Prologue: buf0 full (k0), buf1.B0,B1 (k1). vmcnt(4) completes buf0 k0,
  // leaves buf1.B0,B1 in flight (= steady-state entry invariant).
  STG(Bb, 0, 1, 0, 0); STG(Bb, 0, 1, 1, 0);
  STG(Ab, 0, 0, 0, 0); STG(Ab, 0, 0, 1, 0);
  STG(Bb, 1, 1, 0, 1); STG(Bb, 1, 1, 1, 1);
  VMCNT4();
  BARRIER();

  for (int j = 0; j < 16; ++j) {
    const int k1 = 2 * j + 1;
    const int kt2 = (2 * j + 2 < 32) ? 2 * j + 2 : 31;  // clamped tail stages
    const int kt3 = (2 * j + 3 < 32) ? 2 * j + 3 : 31;  // (valid addr, unused)

#define PH_A_LO_B0(B_, SGB, SGOP, SGH, SGK)                                    \
    /* reads (ks-ordered): [aLo f0,f1 + bB0] x ks; MFMA aLo x g0 */            \
    RA(aLo, 0, 0, 0, B_); RA(aLo, 1, 1, 0, B_); RB(0, 0, B_);                  \
    RA(aLo, 0, 0, 1, B_); RA(aLo, 1, 1, 1, B_); RB(0, 1, B_);                  \
    RA(aLo, 0, 0, 2, B_); RA(aLo, 1, 1, 2, B_); RB(0, 2, B_);                  \
    RA(aLo, 0, 0, 3, B_); RA(aLo, 1, 1, 3, B_); RB(0, 3, B_);                  \
    STG(SGB, SGOP, SGH, SGK >> 16, SGK & 0xffff);                              \
    SCHEDB(); BARRIER();                                                       \
    __builtin_amdgcn_s_setprio(1);                                             \
    LGKM(9); SCHEDB(); MF2(aLo, 0, 0, 0);                                      \
    LGKM(6); SCHEDB(); MF2(aLo, 0, 0, 1);                                      \
    LGKM(3); SCHEDB(); MF2(aLo, 0, 0, 2);                                      \
    LGKM(0); SCHEDB(); MF2(aLo, 0, 0, 3);                                      \
    __builtin_amdgcn_s_setprio(0);                                             \
    SCHEDB(); BARRIER();

#define PH_B1(B_, SGB, SGOP, SGH, SGK)                                         \
    /* reads: bB1 x ks; MFMA aLo x g1 */                                       \
    RB(1, 0, B_); RB(1, 1, B_); RB(1, 2, B_); RB(1, 3, B_);                    \
    STG(SGB, SGOP, SGH, SGK >> 16, SGK & 0xffff);                              \
    SCHEDB(); BARRIER();                                                       \
    __builtin_amdgcn_s_setprio(1);                                             \
    LGKM(3); SCHEDB(); MF2(aLo, 0, 1, 0);                                      \
    LGKM(2); SCHEDB(); MF2(aLo, 0, 1, 1);                                      \
    LGKM(1); SCHEDB(); MF2(aLo, 0, 1, 2);                                      \
    LGKM(0); SCHEDB(); MF2(aLo, 0, 1, 3);                                      \
    __builtin_amdgcn_s_setprio(0);                                             \
    SCHEDB(); BARRIER();

#define PH_A_HI(B_, SGB, SGOP, SGH, SGK)                                       \
    /* reads: aHi f2,f3 x ks; MFMA aHi x g1 */                                 \
    RA(aHi, 0, 2, 0, B_); RA(aHi, 1, 3, 0, B_);                                \
    RA(aHi, 0, 2, 1, B_); RA(aHi, 1, 3, 1, B_);                                \
    RA(aHi, 0, 2, 2, B_); RA(aHi, 1, 3, 2, B_);                                \
    RA(aHi, 0, 2, 3, B_); RA(aHi, 1, 3, 3, B_);                                \
    STG(SGB, SGOP, SGH, SGK >> 16, SGK & 0xffff);                              \
    SCHEDB(); BARRIER();                                                       \
    __builtin_amdgcn_s_setprio(1);                                             \
    LGKM(6); SCHEDB(); MF2(aHi, 2, 1, 0);                                      \
    LGKM(4); SCHEDB(); MF2(aHi, 2, 1, 1);                                      \
    LGKM(2); SCHEDB(); MF2(aHi, 2, 1, 2);                                      \
    LGKM(0); SCHEDB(); MF2(aHi, 2, 1, 3);                                      \
    __builtin_amdgcn_s_setprio(0);                                             \
    SCHEDB(); BARRIER();

#define PH_LAST(SGB, SGOP, SGH, SGK)                                           \
    /* no reads; MFMA aHi x g0; counted vmem wait */                           \
    STG(SGB, SGOP, SGH, SGK >> 16, SGK & 0xffff);                              \
    SCHEDB(); BARRIER(); SCHEDB();                                             \
    __builtin_amdgcn_s_setprio(1);                                             \
    MF2(aHi, 2, 0, 0); MF2(aHi, 2, 0, 1);                                      \
    MF2(aHi, 2, 0, 2); MF2(aHi, 2, 0, 3);                                      \
    __builtin_amdgcn_s_setprio(0);                                             \
    SCHEDB(); VMCNT4(); BARRIER();

    // K-tile 2j on buf0
    PH_A_LO_B0(0, Ab, 1, 0, ((0 << 16) | k1))    // ph1: stage buf1.A0<-k1
    PH_B1    (0, Ab, 1, 0, ((1 << 16) | k1))     // ph2: stage buf1.A1<-k1
    PH_A_HI  (0, Bb, 0, 1, ((0 << 16) | kt2))    // ph3: stage buf0.B0<-kt2
    PH_LAST  (   Bb, 0, 1, ((1 << 16) | kt2))    // ph4: stage buf0.B1<-kt2
    // K-tile 2j+1 on buf1
    PH_A_LO_B0(1, Ab, 0, 0, ((0 << 16) | kt2))   // ph5: stage buf0.A0<-kt2
    PH_B1    (1, Ab, 0, 0, ((1 << 16) | kt2))    // ph6: stage buf0.A1<-kt2
    PH_A_HI  (1, Bb, 1, 1, ((0 << 16) | kt3))    // ph7: stage buf1.B0<-kt3
    PH_LAST  (   Bb, 1, 1, ((1 << 16) | kt3))    // ph8: stage buf1.B1<-kt3
  }

  // drain tail stages before epilogue
  VMCNT0();
  BARRIER();

  // epilogue: C/D col=lane&31, row=(reg&3)+8*(reg>>2)+4*half
  #pragma unroll
  for (int f = 0; f < 4; ++f) {
    #pragma unroll
    for (int g = 0; g < 2; ++g) {
      const int n = n0 + wn * 64 + g * 32 + l5;
      #pragma unroll
      for (int r = 0; r < 16; ++r) {
        const int m = m0 + wm * 128 + f * 32 + (r & 3) + 8 * (r >> 2) + 4 * half;
        out[(size_t)m * N_DIM + n] = acc[f][g][r] + bn[g];
      }
    }
  }
#undef STG
#undef RA
#undef RB
#undef MF2
#undef PH_A_LO_B0
#undef PH_B1
#undef PH_A_HI
#undef PH_LAST
}

// ---------------------------------------------------------------------------
// Fallback GEMM (R1 version): fp32 A converted in-kernel. Used if ws too small.
// ---------------------------------------------------------------------------
#define SA 72
__global__ __launch_bounds__(256) void lora_gemm_fallback(
    const float* __restrict__ X, const bf16_t* __restrict__ Wb,
    const float* __restrict__ bias, float* __restrict__ out) {
  __shared__ __align__(16) bf16_t As[BM * SA];
  __shared__ __align__(16) bf16_t Bs[BN * BK];

  const int t = threadIdx.x;
  const int lane = t & 63;
  const int wv = t >> 6;
  const int wm = wv >> 1, wn = wv & 1;
  const int col = lane & 15, quad = lane >> 4;
  const int m0 = blockIdx.y * BM;
  const int n0 = blockIdx.x * BN;
  const int srow = t >> 3;
  const int soct = t & 7;

  f32x4 acc[4][4] = {};
  float bn[4];
  #pragma unroll
  for (int j = 0; j < 4; ++j) bn[j] = bias[n0 + wn * 64 + j * 16 + col];

  for (int kt = 0; kt < K_DIM / BK; ++kt) {
    const int kg = kt * BK;
    #pragma unroll
    for (int j = 0; j < 4; ++j) {
      int n = j * 32 + srow;
      int c = soct ^ (n & 7);
      async_load16(Wb + (size_t)(n0 + n) * K_DIM + kg + c * 8,
                   &Bs[(size_t)(j * 256 + t) * 8]);
    }
    #pragma unroll
    for (int j = 0; j < 4; ++j) {
      int m = j * 32 + srow;
      const f32x4* src = (const f32x4*)(X + (size_t)(m0 + m) * K_DIM + kg + soct * 8);
      f32x4 lo = src[0], hi = src[1];
      bf16x8 v;
      v[0] = (bf16_t)lo[0]; v[1] = (bf16_t)lo[1];
      v[2] = (bf16_t)lo[2]; v[3] = (bf16_t)lo[3];
      v[4] = (bf16_t)hi[0]; v[5] = (bf16_t)hi[1];
      v[6] = (bf16_t)hi[2]; v[7] = (bf16_t)hi[3];
      *(bf16x8*)&As[m * SA + soct * 8] = v;
    }
    __syncthreads();

    #pragma unroll
    for (int ks = 0; ks < 2; ++ks) {
      bf16x8 af[4], bfr[4];
      #pragma unroll
      for (int i = 0; i < 4; ++i)
        af[i] = *(const bf16x8*)&As[(wm * 64 + i * 16 + col) * SA + ks * 32 + quad * 8];
      #pragma unroll
      for (int j = 0; j < 4; ++j) {
        int n = wn * 64 + j * 16 + col;
        int p = (ks * 4 + quad) ^ (n & 7);
        bfr[j] = *(const bf16x8*)&Bs[n * BK + p * 8];
      }
      #pragma unroll
      for (int i = 0; i < 4; ++i) {
        #pragma unroll
        for (int j = 0; j < 4; ++j)
          acc[i][j] = __builtin_amdgcn_mfma_f32_16x16x32_bf16(af[i], bfr[j], acc[i][j], 0, 0, 0);
      }
    }
    __syncthreads();
  }

  #pragma unroll
  for (int i = 0; i < 4; ++i) {
    #pragma unroll
    for (int r = 0; r < 4; ++r) {
      int m = m0 + wm * 64 + i * 16 + quad * 4 + r;
      float* orow = out + (size_t)m * N_DIM + n0 + wn * 64 + col;
      #pragma unroll
      for (int j = 0; j < 4; ++j)
        orow[j * 16] = acc[i][j][r] + bn[j];
    }
  }
}

extern "C" void kernel_launch(void* const* d_in, const int* in_sizes, int n_in,
                              void* d_out, int out_size, void* d_ws, size_t ws_size,
                              hipStream_t stream) {
  const float* x      = (const float*)d_in[0];
  const float* weight = (const float*)d_in[1];
  const float* bias   = (const float*)d_in[2];
  const float* downs  = (const float*)d_in[3];
  const float* ups    = (const float*)d_in[4];
  const float* scales = (const float*)d_in[5];
  float* out = (float*)d_out;

  const size_t weff_bytes = (size_t)N_DIM * K_DIM * 2;            // 8.4 MB
  const size_t xb_bytes   = (size_t)M_DIM * K_DIM * 2;            // 67 MB
  bf16_t* weff = (bf16_t*)d_ws;

  dim3 g1(K_DIM / 64, N_DIM / 64);
  build_weff_kernel<<<g1, 256, 0, stream>>>(weight, downs, ups, scales, weff);

  if (ws_size >= weff_bytes + xb_bytes) {
    bf16_t* xb = (bf16_t*)((char*)d_ws + weff_bytes);
    const size_t n_elem = (size_t)M_DIM * K_DIM;
    convert_x_kernel<<<(unsigned)(n_elem / (256 * 8)), 256, 0, stream>>>(x, xb);
    gemm_bf16_256<<<dim3((M_DIM / 256) * (N_DIM / 256)), 512, 0, stream>>>(
        xb, weff, bias, out);
  } else {
    dim3 g2(N_DIM / BN, M_DIM / BM);
    lora_gemm_fallback<<<g2, 256, 0, stream>>>(x, weff, bias, out);
  }
}